// Round 1
// baseline (4871.620 us; speedup 1.0000x reference)
//
#include <hip/hip_runtime.h>
#include <math.h>

#define BQ 32
#define SQ 197
#define EQ 768
#define HQ 12
#define DHQ 64
#define FQ 2048
#define LQ 4
#define CQ 1000
#define BSQ (BQ*SQ)   // 6304
#define LN_EPS 1e-5f

// ---------------- LayerNorm: one block per row, E=768 = 3*256 ----------------
__global__ __launch_bounds__(256) void ln_kernel(const float* __restrict__ in,
    const float* __restrict__ w, const float* __restrict__ b,
    float* __restrict__ out)
{
    int row = blockIdx.x;
    const float* x = in + (size_t)row * EQ;
    int t = threadIdx.x;
    float v0 = x[t];
    float v1 = x[t + 256];
    float v2 = x[t + 512];
    __shared__ float red[256];
    red[t] = v0 + v1 + v2;
    __syncthreads();
    for (int off = 128; off > 0; off >>= 1) {
        if (t < off) red[t] += red[t + off];
        __syncthreads();
    }
    float mu = red[0] * (1.0f / EQ);
    __syncthreads();
    float d0 = v0 - mu, d1 = v1 - mu, d2 = v2 - mu;
    red[t] = d0*d0 + d1*d1 + d2*d2;
    __syncthreads();
    for (int off = 128; off > 0; off >>= 1) {
        if (t < off) red[t] += red[t + off];
        __syncthreads();
    }
    float rs = rsqrtf(red[0] * (1.0f / EQ) + LN_EPS);
    float* o = out + (size_t)row * EQ;
    o[t]       = d0 * rs * w[t]       + b[t];
    o[t + 256] = d1 * rs * w[t + 256] + b[t + 256];
    o[t + 512] = d2 * rs * w[t + 512] + b[t + 512];
}

// ---------------- Generic 64x64 tile SGEMM, BK=16, 256 thr, 4x4/thread -------
enum { EPI_NONE = 0, EPI_RES = 1, EPI_BIAS_GELU = 2, EPI_BIAS_RES = 3 };

template<int EPI, bool HEADB>
__global__ __launch_bounds__(256) void gemm64(
    const float* __restrict__ A, const float* __restrict__ Bm,
    float* __restrict__ Cm, const float* __restrict__ bias,
    const float* __restrict__ res, int M, int N, int K)
{
    __shared__ __align__(16) float As[16][68];  // [k][m]
    __shared__ __align__(16) float Bs[16][68];  // [k][n]
    const int tid = threadIdx.x;
    const int tx = tid & 15;
    const int ty = tid >> 4;
    const int row0 = blockIdx.x * 64;
    const int col0 = blockIdx.y * 64;
    // HEADB: B is per-head slab (K x 64) at Bm + head*K*64 (head = blockIdx.y,
    // valid because BN==64==DH and N-tiles align to heads)
    const float* Bb = HEADB ? (Bm + (size_t)blockIdx.y * K * 64) : (Bm + col0);
    const int ldb = HEADB ? 64 : N;

    const int ar = tid >> 2;         // 0..63
    const int ac = (tid & 3) << 2;   // 0,4,8,12
    const int br = tid >> 4;         // 0..15
    const int bc = (tid & 15) << 2;  // 0..60

    float acc[4][4] = {};

    for (int k0 = 0; k0 < K; k0 += 16) {
        float4 av = make_float4(0.f, 0.f, 0.f, 0.f);
        if (row0 + ar < M)
            av = *(const float4*)(A + (size_t)(row0 + ar) * K + k0 + ac);
        As[ac + 0][ar] = av.x; As[ac + 1][ar] = av.y;
        As[ac + 2][ar] = av.z; As[ac + 3][ar] = av.w;
        float4 bv = *(const float4*)(Bb + (size_t)(k0 + br) * ldb + bc);
        *(float4*)&Bs[br][bc] = bv;
        __syncthreads();
        #pragma unroll
        for (int kk = 0; kk < 16; ++kk) {
            float4 a4 = *(const float4*)&As[kk][ty << 2];
            float4 b4 = *(const float4*)&Bs[kk][tx << 2];
            float a[4] = {a4.x, a4.y, a4.z, a4.w};
            float b[4] = {b4.x, b4.y, b4.z, b4.w};
            #pragma unroll
            for (int i = 0; i < 4; ++i)
                #pragma unroll
                for (int j = 0; j < 4; ++j)
                    acc[i][j] = fmaf(a[i], b[j], acc[i][j]);
        }
        __syncthreads();
    }

    #pragma unroll
    for (int i = 0; i < 4; ++i) {
        int r = row0 + (ty << 2) + i;
        if (r >= M) break;
        int c = col0 + (tx << 2);
        size_t idx = (size_t)r * N + c;
        float4 o;
        float vv[4] = {acc[i][0], acc[i][1], acc[i][2], acc[i][3]};
        if (EPI == EPI_NONE) {
            o = make_float4(vv[0], vv[1], vv[2], vv[3]);
        } else if (EPI == EPI_RES) {
            float4 rr = *(const float4*)(res + idx);
            o = make_float4(vv[0] + rr.x, vv[1] + rr.y, vv[2] + rr.z, vv[3] + rr.w);
        } else if (EPI == EPI_BIAS_GELU) {
            float4 bb = *(const float4*)(bias + c);
            float tvals[4] = {vv[0] + bb.x, vv[1] + bb.y, vv[2] + bb.z, vv[3] + bb.w};
            float g[4];
            #pragma unroll
            for (int j = 0; j < 4; ++j)
                g[j] = 0.5f * tvals[j] * (1.0f + erff(tvals[j] * 0.70710678118654752f));
            o = make_float4(g[0], g[1], g[2], g[3]);
        } else { // EPI_BIAS_RES
            float4 bb = *(const float4*)(bias + c);
            float4 rr = *(const float4*)(res + idx);
            o = make_float4(vv[0] + bb.x + rr.x, vv[1] + bb.y + rr.y,
                            vv[2] + bb.z + rr.z, vv[3] + bb.w + rr.w);
        }
        *(float4*)(Cm + idx) = o;
    }
}

// ---------------- scores = scale * q @ k^T, per (b,h), 64x64 tiles -----------
__global__ __launch_bounds__(256) void scores_kernel(
    const float* __restrict__ q, const float* __restrict__ k,
    float* __restrict__ att)
{
    __shared__ __align__(16) float qs[64][68];  // [d][i]
    __shared__ __align__(16) float ks[64][68];  // [d][j]
    int bh = blockIdx.z;
    int b = bh / HQ, h = bh % HQ;
    int i0 = blockIdx.x * 64, j0 = blockIdx.y * 64;
    int tid = threadIdx.x;
    for (int p = tid; p < 64 * 16; p += 256) {
        int r = p >> 4, d4 = (p & 15) << 2;
        float4 v = make_float4(0.f, 0.f, 0.f, 0.f);
        if (i0 + r < SQ)
            v = *(const float4*)(q + (size_t)(b * SQ + i0 + r) * EQ + h * DHQ + d4);
        qs[d4 + 0][r] = v.x; qs[d4 + 1][r] = v.y;
        qs[d4 + 2][r] = v.z; qs[d4 + 3][r] = v.w;
        float4 u = make_float4(0.f, 0.f, 0.f, 0.f);
        if (j0 + r < SQ)
            u = *(const float4*)(k + (size_t)(b * SQ + j0 + r) * EQ + h * DHQ + d4);
        ks[d4 + 0][r] = u.x; ks[d4 + 1][r] = u.y;
        ks[d4 + 2][r] = u.z; ks[d4 + 3][r] = u.w;
    }
    __syncthreads();
    int tx = tid & 15, ty = tid >> 4;
    float acc[4][4] = {};
    #pragma unroll 16
    for (int d = 0; d < 64; ++d) {
        float4 a4 = *(const float4*)&qs[d][ty << 2];
        float4 b4 = *(const float4*)&ks[d][tx << 2];
        float a[4] = {a4.x, a4.y, a4.z, a4.w};
        float b[4] = {b4.x, b4.y, b4.z, b4.w};
        #pragma unroll
        for (int i = 0; i < 4; ++i)
            #pragma unroll
            for (int j = 0; j < 4; ++j)
                acc[i][j] = fmaf(a[i], b[j], acc[i][j]);
    }
    const float scale = 0.07124704998790965f; // 1/sqrt(197)
    #pragma unroll
    for (int i = 0; i < 4; ++i) {
        int i_ = i0 + (ty << 2) + i;
        if (i_ >= SQ) break;
        #pragma unroll
        for (int j = 0; j < 4; ++j) {
            int j_ = j0 + (tx << 2) + j;
            if (j_ < SQ)
                att[((size_t)bh * SQ + i_) * SQ + j_] = acc[i][j] * scale;
        }
    }
}

// ---------------- row softmax over 197, one wave per row ---------------------
__global__ __launch_bounds__(64) void softmax_kernel(float* __restrict__ att)
{
    size_t row = blockIdx.x;
    float* p = att + row * SQ;
    int t = threadIdx.x;
    float x0 = p[t];
    float x1 = p[t + 64];
    float x2 = p[t + 128];
    bool ok3 = (t + 192) < SQ;
    float x3 = ok3 ? p[t + 192] : -1e30f;
    float m = fmaxf(fmaxf(x0, x1), fmaxf(x2, x3));
    for (int off = 32; off; off >>= 1) m = fmaxf(m, __shfl_xor(m, off));
    float e0 = expf(x0 - m), e1 = expf(x1 - m), e2 = expf(x2 - m);
    float e3 = ok3 ? expf(x3 - m) : 0.f;
    float s = e0 + e1 + e2 + e3;
    for (int off = 32; off; off >>= 1) s += __shfl_xor(s, off);
    float inv = 1.0f / s;
    p[t] = e0 * inv;
    p[t + 64] = e1 * inv;
    p[t + 128] = e2 * inv;
    if (ok3) p[t + 192] = e3 * inv;
}

// ---------------- o = att @ v, per (b,h), 64(s) x 64(d), BK=32 ---------------
__global__ __launch_bounds__(256) void attv_kernel(
    const float* __restrict__ att, const float* __restrict__ v,
    float* __restrict__ o)
{
    __shared__ __align__(16) float As[32][68]; // [j][s]
    __shared__ __align__(16) float Bs[32][68]; // [j][d]
    int bh = blockIdx.y;
    int b = bh / HQ, h = bh % HQ;
    int s0 = blockIdx.x * 64;
    int tid = threadIdx.x;
    int tx = tid & 15, ty = tid >> 4;
    float acc[4][4] = {};
    for (int k0 = 0; k0 < SQ; k0 += 32) {
        for (int p = tid; p < 64 * 32; p += 256) {
            int s_ = p >> 5, j_ = p & 31;
            float val = 0.f;
            if (s0 + s_ < SQ && k0 + j_ < SQ)
                val = att[((size_t)bh * SQ + s0 + s_) * SQ + k0 + j_];
            As[j_][s_] = val;
        }
        for (int p = tid; p < 32 * 16; p += 256) {
            int j_ = p >> 4, d4 = (p & 15) << 2;
            float4 u = make_float4(0.f, 0.f, 0.f, 0.f);
            if (k0 + j_ < SQ)
                u = *(const float4*)(v + (size_t)(b * SQ + k0 + j_) * EQ + h * DHQ + d4);
            *(float4*)&Bs[j_][d4] = u;
        }
        __syncthreads();
        #pragma unroll
        for (int kk = 0; kk < 32; ++kk) {
            float4 a4 = *(const float4*)&As[kk][ty << 2];
            float4 b4 = *(const float4*)&Bs[kk][tx << 2];
            float a[4] = {a4.x, a4.y, a4.z, a4.w};
            float b[4] = {b4.x, b4.y, b4.z, b4.w};
            #pragma unroll
            for (int i = 0; i < 4; ++i)
                #pragma unroll
                for (int j = 0; j < 4; ++j)
                    acc[i][j] = fmaf(a[i], b[j], acc[i][j]);
        }
        __syncthreads();
    }
    #pragma unroll
    for (int i = 0; i < 4; ++i) {
        int s_ = s0 + (ty << 2) + i;
        if (s_ >= SQ) break;
        float4 ov = make_float4(acc[i][0], acc[i][1], acc[i][2], acc[i][3]);
        *(float4*)(o + (size_t)(b * SQ + s_) * EQ + h * DHQ + (tx << 2)) = ov;
    }
}

// ---------------- classifier: logits GEMM + softmax, one block per b ---------
__global__ __launch_bounds__(256) void cls_kernel(
    const float* __restrict__ hbuf, const float* __restrict__ Wc,
    const float* __restrict__ bc, float* __restrict__ out)
{
    __shared__ __align__(16) float hs[768];
    __shared__ float red[256];
    int b = blockIdx.x;
    int tid = threadIdx.x;
    const float* hr = hbuf + (size_t)(b * SQ) * EQ;  // s = 0 row
    for (int p = tid; p < 192; p += 256)
        *(float4*)&hs[p << 2] = *(const float4*)(hr + (p << 2));
    __syncthreads();
    float lg[4];
    int cidx[4];
    #pragma unroll
    for (int j = 0; j < 4; ++j) { cidx[j] = tid + 256 * j; lg[j] = -1e30f; }
    #pragma unroll
    for (int j = 0; j < 4; ++j) {
        int c = cidx[j];
        if (c < CQ) {
            float s = bc[c];
            for (int e = 0; e < EQ; ++e)
                s = fmaf(hs[e], Wc[(size_t)e * CQ + c], s);
            lg[j] = s;
        }
    }
    float m = fmaxf(fmaxf(lg[0], lg[1]), fmaxf(lg[2], lg[3]));
    red[tid] = m;
    __syncthreads();
    for (int off = 128; off; off >>= 1) {
        if (tid < off) red[tid] = fmaxf(red[tid], red[tid + off]);
        __syncthreads();
    }
    m = red[0];
    __syncthreads();
    float ex[4];
    float s = 0.f;
    #pragma unroll
    for (int j = 0; j < 4; ++j) {
        ex[j] = (cidx[j] < CQ) ? expf(lg[j] - m) : 0.f;
        s += ex[j];
    }
    red[tid] = s;
    __syncthreads();
    for (int off = 128; off; off >>= 1) {
        if (tid < off) red[tid] += red[tid + off];
        __syncthreads();
    }
    float inv = 1.0f / red[0];
    #pragma unroll
    for (int j = 0; j < 4; ++j)
        if (cidx[j] < CQ) out[(size_t)b * CQ + cidx[j]] = ex[j] * inv;
}

extern "C" void kernel_launch(void* const* d_in, const int* in_sizes, int n_in,
                              void* d_out, int out_size, void* d_ws, size_t ws_size,
                              hipStream_t stream)
{
    const float* x     = (const float*)d_in[0];
    const float* Wk    = (const float*)d_in[1];
    const float* Wq    = (const float*)d_in[2];
    const float* Wv    = (const float*)d_in[3];
    const float* Wconv = (const float*)d_in[4];
    const float* ln1w  = (const float*)d_in[5];
    const float* ln1b  = (const float*)d_in[6];
    const float* ln2w  = (const float*)d_in[7];
    const float* ln2b  = (const float*)d_in[8];
    const float* W1    = (const float*)d_in[9];
    const float* b1    = (const float*)d_in[10];
    const float* W2    = (const float*)d_in[11];
    const float* b2    = (const float*)d_in[12];
    const float* Wc    = (const float*)d_in[13];
    const float* bc    = (const float*)d_in[14];
    float* out = (float*)d_out;

    const size_t BSE  = (size_t)BSQ * EQ;            // 4,841,472
    const size_t BHSS = (size_t)BQ * HQ * SQ * SQ;   // 14,902,656
    float* w = (float*)d_ws;
    float* bh  = w; w += BSE;   // residual stream (output of each layer)
    float* xn  = w; w += BSE;   // ln1 out, reused as attention output o
    float* qb  = w; w += BSE;   // q, reused as res1
    float* kb  = w; w += BSE;   // k, reused as xn2
    float* vb  = w; w += BSE;   // v
    float* att = w; w += BHSS;  // scores/att, reused as ff hidden (12.9M < 14.9M)

    dim3 g99_12(99, 12), g99_32(99, 32);

    for (int l = 0; l < LQ; ++l) {
        const float* hin = (l == 0) ? x : bh;
        ln_kernel<<<BSQ, 256, 0, stream>>>(hin, ln1w + l * EQ, ln1b + l * EQ, xn);
        gemm64<EPI_NONE, true><<<g99_12, 256, 0, stream>>>(
            xn, Wq + (size_t)l * HQ * EQ * DHQ, qb, nullptr, nullptr, BSQ, EQ, EQ);
        gemm64<EPI_NONE, true><<<g99_12, 256, 0, stream>>>(
            xn, Wk + (size_t)l * HQ * EQ * DHQ, kb, nullptr, nullptr, BSQ, EQ, EQ);
        gemm64<EPI_NONE, true><<<g99_12, 256, 0, stream>>>(
            xn, Wv + (size_t)l * HQ * EQ * DHQ, vb, nullptr, nullptr, BSQ, EQ, EQ);
        scores_kernel<<<dim3(4, 4, BQ * HQ), 256, 0, stream>>>(qb, kb, att);
        softmax_kernel<<<BQ * HQ * SQ, 64, 0, stream>>>(att);
        attv_kernel<<<dim3(4, BQ * HQ), 256, 0, stream>>>(att, vb, xn); // o -> xn
        gemm64<EPI_RES, false><<<g99_12, 256, 0, stream>>>(
            xn, Wconv + (size_t)l * EQ * EQ, qb /*res1*/, nullptr, hin, BSQ, EQ, EQ);
        ln_kernel<<<BSQ, 256, 0, stream>>>(qb, ln2w + l * EQ, ln2b + l * EQ, kb);
        gemm64<EPI_BIAS_GELU, false><<<g99_32, 256, 0, stream>>>(
            kb, W1 + (size_t)l * EQ * FQ, att /*ff hidden*/, b1 + l * FQ, nullptr,
            BSQ, FQ, EQ);
        gemm64<EPI_BIAS_RES, false><<<g99_12, 256, 0, stream>>>(
            att, W2 + (size_t)l * FQ * EQ, bh, b2 + l * EQ, qb /*res1*/,
            BSQ, EQ, FQ);
    }
    cls_kernel<<<BQ, 256, 0, stream>>>(bh, Wc, bc, out);
}

// Round 2
// 1951.857 us; speedup vs baseline: 2.4959x; 2.4959x over previous
//
#include <hip/hip_runtime.h>
#include <hip/hip_bf16.h>
#include <math.h>

#define BQ 32
#define SQ 197
#define EQ 768
#define HQ 12
#define DHQ 64
#define FQ 2048
#define LQ 4
#define CQ 1000
#define BSQ (BQ*SQ)     // 6304
#define MPAD 6400       // 6304 padded to 128-multiple for MFMA A-tiles
#define LN_EPS 1e-5f

typedef __bf16 bf16x8 __attribute__((ext_vector_type(8)));
typedef float f32x4 __attribute__((ext_vector_type(4)));

typedef __attribute__((address_space(1))) void gvoid;
typedef __attribute__((address_space(3))) void lvoid;

__device__ __forceinline__ void async16(const void* g, void* l) {
    __builtin_amdgcn_global_load_lds((gvoid*)g, (lvoid*)l, 16, 0, 0);
}

// ---------------- transpose + fp32->bf16 convert: out[c][r] = in[r][c] ------
// in: slab of R x C fp32 (row-major); out: slab of C x R bf16 (row-major)
__global__ __launch_bounds__(256) void tconv(const float* __restrict__ in,
    __hip_bfloat16* __restrict__ out, int R, int C, size_t slab)
{
    __shared__ float tile[64][65];
    const float* ip = in + (size_t)blockIdx.z * slab;
    __hip_bfloat16* op = out + (size_t)blockIdx.z * slab;
    int r0 = blockIdx.x * 64, c0 = blockIdx.y * 64;
    int t = threadIdx.x;
    int tc = t & 63, tr = t >> 6;
    #pragma unroll
    for (int p = 0; p < 16; ++p) {
        int r = p * 4 + tr;
        tile[r][tc] = ip[(size_t)(r0 + r) * C + c0 + tc];
    }
    __syncthreads();
    #pragma unroll
    for (int p = 0; p < 16; ++p) {
        int c = p * 4 + tr;
        op[(size_t)(c0 + c) * R + r0 + tc] = __float2bfloat16(tile[tc][c]);
    }
}

// ---------------- LayerNorm: fp32 in -> bf16 out, one block per row ---------
__global__ __launch_bounds__(256) void ln_kernel(const float* __restrict__ in,
    const float* __restrict__ w, const float* __restrict__ b,
    __hip_bfloat16* __restrict__ out)
{
    int row = blockIdx.x;
    const float* x = in + (size_t)row * EQ;
    int t = threadIdx.x;
    float v0 = x[t];
    float v1 = x[t + 256];
    float v2 = x[t + 512];
    __shared__ float red[256];
    red[t] = v0 + v1 + v2;
    __syncthreads();
    for (int off = 128; off > 0; off >>= 1) {
        if (t < off) red[t] += red[t + off];
        __syncthreads();
    }
    float mu = red[0] * (1.0f / EQ);
    __syncthreads();
    float d0 = v0 - mu, d1 = v1 - mu, d2 = v2 - mu;
    red[t] = d0*d0 + d1*d1 + d2*d2;
    __syncthreads();
    for (int off = 128; off > 0; off >>= 1) {
        if (t < off) red[t] += red[t + off];
        __syncthreads();
    }
    float rs = rsqrtf(red[0] * (1.0f / EQ) + LN_EPS);
    __hip_bfloat16* o = out + (size_t)row * EQ;
    o[t]       = __float2bfloat16(d0 * rs * w[t]       + b[t]);
    o[t + 256] = __float2bfloat16(d1 * rs * w[t + 256] + b[t + 256]);
    o[t + 512] = __float2bfloat16(d2 * rs * w[t + 512] + b[t + 512]);
}

// ---------------- bf16 MFMA GEMM: C = A(MxK) @ Bt(NxK)^T, 128x128 tile ------
// A padded to >= gridDim.x*128 rows. 256 thr = 4 waves in 2x2; each wave 64x64.
enum { EPI_NONE = 0, EPI_RES = 1, EPI_BIAS_GELU = 2, EPI_BIAS_RES = 3 };

template<int EPI, bool OUTBF16>
__global__ __launch_bounds__(256) void mgemm(
    const void* __restrict__ A, const void* __restrict__ Bt,
    void* __restrict__ Cm, const float* __restrict__ bias,
    const float* __restrict__ res, int M, int N, int K)
{
    __shared__ __align__(16) unsigned short As[128 * 32];  // rows of 32 bf16 (64B)
    __shared__ __align__(16) unsigned short Bs[128 * 32];
    const int tid = threadIdx.x;
    const int lane = tid & 63;
    const int w = tid >> 6;
    const int wr = w >> 1, wc = w & 1;
    const int l15 = lane & 15, quad = lane >> 4;
    const int row0 = blockIdx.x * 128, col0 = blockIdx.y * 128;

    f32x4 acc[4][4] = {};

    const char* Ab = (const char*)A;
    const char* Bb = (const char*)Bt;

    for (int k0 = 0; k0 < K; k0 += 32) {
        #pragma unroll
        for (int c = 0; c < 2; ++c) {
            int ch = c * 256 + tid;                  // 16B chunk id, 4 per row
            const char* ga = Ab + ((size_t)(row0 + (ch >> 2)) * K + k0) * 2 + (ch & 3) * 16;
            async16(ga, (char*)As + (size_t)(c * 256 + w * 64) * 16);
            const char* gb = Bb + ((size_t)(col0 + (ch >> 2)) * K + k0) * 2 + (ch & 3) * 16;
            async16(gb, (char*)Bs + (size_t)(c * 256 + w * 64) * 16);
        }
        __syncthreads();
        bf16x8 af[4], bf[4];
        #pragma unroll
        for (int i = 0; i < 4; ++i)
            af[i] = *(const bf16x8*)&As[(wr * 64 + i * 16 + l15) * 32 + quad * 8];
        #pragma unroll
        for (int j = 0; j < 4; ++j)
            bf[j] = *(const bf16x8*)&Bs[(wc * 64 + j * 16 + l15) * 32 + quad * 8];
        #pragma unroll
        for (int i = 0; i < 4; ++i)
            #pragma unroll
            for (int j = 0; j < 4; ++j)
                acc[i][j] = __builtin_amdgcn_mfma_f32_16x16x32_bf16(af[i], bf[j], acc[i][j], 0, 0, 0);
        __syncthreads();
    }

    #pragma unroll
    for (int j = 0; j < 4; ++j) {
        int c = col0 + wc * 64 + j * 16 + l15;
        float bv = 0.f;
        if (EPI == EPI_BIAS_GELU || EPI == EPI_BIAS_RES) bv = bias[c];
        #pragma unroll
        for (int i = 0; i < 4; ++i) {
            #pragma unroll
            for (int rg = 0; rg < 4; ++rg) {
                int r = row0 + wr * 64 + i * 16 + quad * 4 + rg;
                if (r < M) {
                    float v = acc[i][j][rg];
                    size_t idx = (size_t)r * N + c;
                    if (EPI == EPI_RES) {
                        v += res[idx];
                    } else if (EPI == EPI_BIAS_GELU) {
                        v += bv;
                        v = 0.5f * v * (1.0f + erff(v * 0.70710678118654752f));
                    } else if (EPI == EPI_BIAS_RES) {
                        v += bv + res[idx];
                    }
                    if (OUTBF16) ((__hip_bfloat16*)Cm)[idx] = __float2bfloat16(v);
                    else         ((float*)Cm)[idx] = v;
                }
            }
        }
    }
}

// ---------------- scores = scale * q @ k^T, per (b,h), fp32 -----------------
__global__ __launch_bounds__(256) void scores_kernel(
    const float* __restrict__ q, const float* __restrict__ k,
    float* __restrict__ att)
{
    __shared__ __align__(16) float qs[64][68];
    __shared__ __align__(16) float ks[64][68];
    int bh = blockIdx.z;
    int b = bh / HQ, h = bh % HQ;
    int i0 = blockIdx.x * 64, j0 = blockIdx.y * 64;
    int tid = threadIdx.x;
    for (int p = tid; p < 64 * 16; p += 256) {
        int r = p >> 4, d4 = (p & 15) << 2;
        float4 v = make_float4(0.f, 0.f, 0.f, 0.f);
        if (i0 + r < SQ)
            v = *(const float4*)(q + (size_t)(b * SQ + i0 + r) * EQ + h * DHQ + d4);
        qs[d4 + 0][r] = v.x; qs[d4 + 1][r] = v.y;
        qs[d4 + 2][r] = v.z; qs[d4 + 3][r] = v.w;
        float4 u = make_float4(0.f, 0.f, 0.f, 0.f);
        if (j0 + r < SQ)
            u = *(const float4*)(k + (size_t)(b * SQ + j0 + r) * EQ + h * DHQ + d4);
        ks[d4 + 0][r] = u.x; ks[d4 + 1][r] = u.y;
        ks[d4 + 2][r] = u.z; ks[d4 + 3][r] = u.w;
    }
    __syncthreads();
    int tx = tid & 15, ty = tid >> 4;
    float acc[4][4] = {};
    #pragma unroll 16
    for (int d = 0; d < 64; ++d) {
        float4 a4 = *(const float4*)&qs[d][ty << 2];
        float4 b4 = *(const float4*)&ks[d][tx << 2];
        float a[4] = {a4.x, a4.y, a4.z, a4.w};
        float bb[4] = {b4.x, b4.y, b4.z, b4.w};
        #pragma unroll
        for (int i = 0; i < 4; ++i)
            #pragma unroll
            for (int j = 0; j < 4; ++j)
                acc[i][j] = fmaf(a[i], bb[j], acc[i][j]);
    }
    const float scale = 0.07124704998790965f; // 1/sqrt(197)
    #pragma unroll
    for (int i = 0; i < 4; ++i) {
        int i_ = i0 + (ty << 2) + i;
        if (i_ >= SQ) break;
        #pragma unroll
        for (int j = 0; j < 4; ++j) {
            int j_ = j0 + (tx << 2) + j;
            if (j_ < SQ)
                att[((size_t)bh * SQ + i_) * SQ + j_] = acc[i][j] * scale;
        }
    }
}

// ---------------- row softmax over 197, one wave per row --------------------
__global__ __launch_bounds__(64) void softmax_kernel(float* __restrict__ att)
{
    size_t row = blockIdx.x;
    float* p = att + row * SQ;
    int t = threadIdx.x;
    float x0 = p[t];
    float x1 = p[t + 64];
    float x2 = p[t + 128];
    bool ok3 = (t + 192) < SQ;
    float x3 = ok3 ? p[t + 192] : -1e30f;
    float m = fmaxf(fmaxf(x0, x1), fmaxf(x2, x3));
    for (int off = 32; off; off >>= 1) m = fmaxf(m, __shfl_xor(m, off));
    float e0 = expf(x0 - m), e1 = expf(x1 - m), e2 = expf(x2 - m);
    float e3 = ok3 ? expf(x3 - m) : 0.f;
    float s = e0 + e1 + e2 + e3;
    for (int off = 32; off; off >>= 1) s += __shfl_xor(s, off);
    float inv = 1.0f / s;
    p[t] = e0 * inv;
    p[t + 64] = e1 * inv;
    p[t + 128] = e2 * inv;
    if (ok3) p[t + 192] = e3 * inv;
}

// ---------------- o = att @ v, per (b,h), fp32 acc -> bf16 out --------------
__global__ __launch_bounds__(256) void attv_kernel(
    const float* __restrict__ att, const float* __restrict__ v,
    __hip_bfloat16* __restrict__ o)
{
    __shared__ __align__(16) float As[32][68];
    __shared__ __align__(16) float Bs[32][68];
    int bh = blockIdx.y;
    int b = bh / HQ, h = bh % HQ;
    int s0 = blockIdx.x * 64;
    int tid = threadIdx.x;
    int tx = tid & 15, ty = tid >> 4;
    float acc[4][4] = {};
    for (int k0 = 0; k0 < SQ; k0 += 32) {
        for (int p = tid; p < 64 * 32; p += 256) {
            int s_ = p >> 5, j_ = p & 31;
            float val = 0.f;
            if (s0 + s_ < SQ && k0 + j_ < SQ)
                val = att[((size_t)bh * SQ + s0 + s_) * SQ + k0 + j_];
            As[j_][s_] = val;
        }
        for (int p = tid; p < 32 * 16; p += 256) {
            int j_ = p >> 4, d4 = (p & 15) << 2;
            float4 u = make_float4(0.f, 0.f, 0.f, 0.f);
            if (k0 + j_ < SQ)
                u = *(const float4*)(v + (size_t)(b * SQ + k0 + j_) * EQ + h * DHQ + d4);
            *(float4*)&Bs[j_][d4] = u;
        }
        __syncthreads();
        #pragma unroll
        for (int kk = 0; kk < 32; ++kk) {
            float4 a4 = *(const float4*)&As[kk][ty << 2];
            float4 b4 = *(const float4*)&Bs[kk][tx << 2];
            float a[4] = {a4.x, a4.y, a4.z, a4.w};
            float bb[4] = {b4.x, b4.y, b4.z, b4.w};
            #pragma unroll
            for (int i = 0; i < 4; ++i)
                #pragma unroll
                for (int j = 0; j < 4; ++j)
                    acc[i][j] = fmaf(a[i], bb[j], acc[i][j]);
        }
        __syncthreads();
    }
    #pragma unroll
    for (int i = 0; i < 4; ++i) {
        int s_ = s0 + (ty << 2) + i;
        if (s_ >= SQ) break;
        __hip_bfloat16* op = o + (size_t)(b * SQ + s_) * EQ + h * DHQ + (tx << 2);
        #pragma unroll
        for (int j = 0; j < 4; ++j)
            op[j] = __float2bfloat16(acc[i][j]);
    }
}

// ---------------- classifier: logits GEMM + softmax, fp32 -------------------
__global__ __launch_bounds__(256) void cls_kernel(
    const float* __restrict__ hbuf, const float* __restrict__ Wc,
    const float* __restrict__ bc, float* __restrict__ out)
{
    __shared__ __align__(16) float hs[768];
    __shared__ float red[256];
    int b = blockIdx.x;
    int tid = threadIdx.x;
    const float* hr = hbuf + (size_t)(b * SQ) * EQ;
    for (int p = tid; p < 192; p += 256)
        *(float4*)&hs[p << 2] = *(const float4*)(hr + (p << 2));
    __syncthreads();
    float lg[4];
    int cidx[4];
    #pragma unroll
    for (int j = 0; j < 4; ++j) { cidx[j] = tid + 256 * j; lg[j] = -1e30f; }
    #pragma unroll
    for (int j = 0; j < 4; ++j) {
        int c = cidx[j];
        if (c < CQ) {
            float s = bc[c];
            for (int e = 0; e < EQ; ++e)
                s = fmaf(hs[e], Wc[(size_t)e * CQ + c], s);
            lg[j] = s;
        }
    }
    float m = fmaxf(fmaxf(lg[0], lg[1]), fmaxf(lg[2], lg[3]));
    red[tid] = m;
    __syncthreads();
    for (int off = 128; off; off >>= 1) {
        if (tid < off) red[tid] = fmaxf(red[tid], red[tid + off]);
        __syncthreads();
    }
    m = red[0];
    __syncthreads();
    float ex[4];
    float s = 0.f;
    #pragma unroll
    for (int j = 0; j < 4; ++j) {
        ex[j] = (cidx[j] < CQ) ? expf(lg[j] - m) : 0.f;
        s += ex[j];
    }
    red[tid] = s;
    __syncthreads();
    for (int off = 128; off; off >>= 1) {
        if (tid < off) red[tid] += red[tid + off];
        __syncthreads();
    }
    float inv = 1.0f / red[0];
    #pragma unroll
    for (int j = 0; j < 4; ++j)
        if (cidx[j] < CQ) out[(size_t)b * CQ + cidx[j]] = ex[j] * inv;
}

extern "C" void kernel_launch(void* const* d_in, const int* in_sizes, int n_in,
                              void* d_out, int out_size, void* d_ws, size_t ws_size,
                              hipStream_t stream)
{
    const float* x     = (const float*)d_in[0];
    const float* Wk    = (const float*)d_in[1];
    const float* Wq    = (const float*)d_in[2];
    const float* Wv    = (const float*)d_in[3];
    const float* Wconv = (const float*)d_in[4];
    const float* ln1w  = (const float*)d_in[5];
    const float* ln1b  = (const float*)d_in[6];
    const float* ln2w  = (const float*)d_in[7];
    const float* ln2b  = (const float*)d_in[8];
    const float* W1    = (const float*)d_in[9];
    const float* b1    = (const float*)d_in[10];
    const float* W2    = (const float*)d_in[11];
    const float* b2    = (const float*)d_in[12];
    const float* Wc    = (const float*)d_in[13];
    const float* bc    = (const float*)d_in[14];
    float* out = (float*)d_out;

    const size_t BSE  = (size_t)BSQ * EQ;            // 4,841,472
    const size_t BSEp = (size_t)MPAD * EQ;           // 4,915,200 (bf16 elems)
    const size_t BHSS = (size_t)BQ * HQ * SQ * SQ;   // 14,902,656

    float* w = (float*)d_ws;
    float* bh  = w; w += BSE;    // residual stream output
    float* qb  = w; w += BSE;    // q, reused as res1
    float* kb  = w; w += BSE;    // k
    float* vb  = w; w += BSE;    // v
    float* att = w; w += BHSS;   // scores/att; later overlaid by ffh (bf16)
    __hip_bfloat16* actb = (__hip_bfloat16*)w;          // xn -> o -> xn2 (padded)
    __hip_bfloat16* wbuf = actb + BSEp;                 // weight bf16 buffer
    __hip_bfloat16* ffh  = (__hip_bfloat16*)att;        // MPAD x F bf16 (26.2MB <= 59.6MB)

    const size_t WQKV = (size_t)EQ * EQ;   // 589,824 per tensor per layer
    __hip_bfloat16* WqT = wbuf;
    __hip_bfloat16* WkT = wbuf + WQKV;
    __hip_bfloat16* WvT = wbuf + 2 * WQKV;
    __hip_bfloat16* WcvT = wbuf;                       // phase B overlays
    __hip_bfloat16* W1T  = wbuf + WQKV;
    __hip_bfloat16* W2T  = W1T + (size_t)EQ * FQ;

    for (int l = 0; l < LQ; ++l) {
        const float* hin = (l == 0) ? x : bh;
        // phase A weights: Wq/Wk/Wv (per-head 768x64 transposes)
        tconv<<<dim3(12, 1, HQ), 256, 0, stream>>>(Wq + (size_t)l * HQ * EQ * DHQ, WqT, EQ, DHQ, (size_t)EQ * DHQ);
        tconv<<<dim3(12, 1, HQ), 256, 0, stream>>>(Wk + (size_t)l * HQ * EQ * DHQ, WkT, EQ, DHQ, (size_t)EQ * DHQ);
        tconv<<<dim3(12, 1, HQ), 256, 0, stream>>>(Wv + (size_t)l * HQ * EQ * DHQ, WvT, EQ, DHQ, (size_t)EQ * DHQ);

        ln_kernel<<<BSQ, 256, 0, stream>>>(hin, ln1w + l * EQ, ln1b + l * EQ, actb);

        mgemm<EPI_NONE, false><<<dim3(50, 6), 256, 0, stream>>>(actb, WqT, qb, nullptr, nullptr, BSQ, EQ, EQ);
        mgemm<EPI_NONE, false><<<dim3(50, 6), 256, 0, stream>>>(actb, WkT, kb, nullptr, nullptr, BSQ, EQ, EQ);
        mgemm<EPI_NONE, false><<<dim3(50, 6), 256, 0, stream>>>(actb, WvT, vb, nullptr, nullptr, BSQ, EQ, EQ);

        // phase B weights: Wconv, W1, W2 (wbuf free after QKV GEMMs, stream order)
        tconv<<<dim3(12, 12, 1), 256, 0, stream>>>(Wconv + (size_t)l * EQ * EQ, WcvT, EQ, EQ, 0);
        tconv<<<dim3(12, 32, 1), 256, 0, stream>>>(W1 + (size_t)l * EQ * FQ, W1T, EQ, FQ, 0);
        tconv<<<dim3(32, 12, 1), 256, 0, stream>>>(W2 + (size_t)l * FQ * EQ, W2T, FQ, EQ, 0);

        scores_kernel<<<dim3(4, 4, BQ * HQ), 256, 0, stream>>>(qb, kb, att);
        softmax_kernel<<<BQ * HQ * SQ, 64, 0, stream>>>(att);
        attv_kernel<<<dim3(4, BQ * HQ), 256, 0, stream>>>(att, vb, actb);   // o (bf16)

        mgemm<EPI_RES, false><<<dim3(50, 6), 256, 0, stream>>>(actb, WcvT, qb /*res1*/, nullptr, hin, BSQ, EQ, EQ);

        ln_kernel<<<BSQ, 256, 0, stream>>>(qb, ln2w + l * EQ, ln2b + l * EQ, actb);

        mgemm<EPI_BIAS_GELU, true><<<dim3(50, 16), 256, 0, stream>>>(actb, W1T, ffh, b1 + l * FQ, nullptr, BSQ, FQ, EQ);
        mgemm<EPI_BIAS_RES, false><<<dim3(50, 6), 256, 0, stream>>>(ffh, W2T, bh, b2 + l * EQ, qb /*res1*/, BSQ, EQ, FQ);
    }
    cls_kernel<<<BQ, 256, 0, stream>>>(bh, Wc, bc, out);
}

// Round 3
// 1508.684 us; speedup vs baseline: 3.2291x; 1.2937x over previous
//
#include <hip/hip_runtime.h>
#include <hip/hip_bf16.h>
#include <math.h>

#define BQ 32
#define SQ 197
#define EQ 768
#define HQ 12
#define DHQ 64
#define FQ 2048
#define LQ 4
#define CQ 1000
#define BSQ (BQ*SQ)     // 6304
#define MPAD 6400       // 6304 padded to 128-multiple for MFMA A-tiles
#define QKV3 2304       // fused q|k|v row width
#define TPAD 256        // attention t-dim padded
#define LN_EPS 1e-5f

typedef __bf16 bf16x8 __attribute__((ext_vector_type(8)));
typedef float f32x4 __attribute__((ext_vector_type(4)));

typedef __attribute__((address_space(1))) void gvoid;
typedef __attribute__((address_space(3))) void lvoid;

__device__ __forceinline__ void async16(const void* g, void* l) {
    __builtin_amdgcn_global_load_lds((gvoid*)g, (lvoid*)l, 16, 0, 0);
}

__device__ __forceinline__ __hip_bfloat16 tobf(float f) { return __float2bfloat16(f); }

// ---------------- transpose + fp32->bf16 convert: out[c][r] = in[r][c] ------
__global__ __launch_bounds__(256) void tconv(const float* __restrict__ in,
    __hip_bfloat16* __restrict__ out, int R, int C, size_t slab)
{
    __shared__ float tile[64][65];
    const float* ip = in + (size_t)blockIdx.z * slab;
    __hip_bfloat16* op = out + (size_t)blockIdx.z * slab;
    int r0 = blockIdx.x * 64, c0 = blockIdx.y * 64;
    int t = threadIdx.x;
    int tc = t & 63, tr = t >> 6;
    #pragma unroll
    for (int p = 0; p < 16; ++p) {
        int r = p * 4 + tr;
        tile[r][tc] = ip[(size_t)(r0 + r) * C + c0 + tc];
    }
    __syncthreads();
    #pragma unroll
    for (int p = 0; p < 16; ++p) {
        int c = p * 4 + tr;
        op[(size_t)(c0 + c) * R + r0 + tc] = tobf(tile[tc][c]);
    }
}

// ---------------- LayerNorm: fp32 in -> bf16 out ----------------------------
__global__ __launch_bounds__(256) void ln_kernel(const float* __restrict__ in,
    const float* __restrict__ w, const float* __restrict__ b,
    __hip_bfloat16* __restrict__ out)
{
    int row = blockIdx.x;
    const float* x = in + (size_t)row * EQ;
    int t = threadIdx.x;
    float v0 = x[t];
    float v1 = x[t + 256];
    float v2 = x[t + 512];
    __shared__ float red[256];
    red[t] = v0 + v1 + v2;
    __syncthreads();
    for (int off = 128; off > 0; off >>= 1) {
        if (t < off) red[t] += red[t + off];
        __syncthreads();
    }
    float mu = red[0] * (1.0f / EQ);
    __syncthreads();
    float d0 = v0 - mu, d1 = v1 - mu, d2 = v2 - mu;
    red[t] = d0*d0 + d1*d1 + d2*d2;
    __syncthreads();
    for (int off = 128; off > 0; off >>= 1) {
        if (t < off) red[t] += red[t + off];
        __syncthreads();
    }
    float rs = rsqrtf(red[0] * (1.0f / EQ) + LN_EPS);
    __hip_bfloat16* o = out + (size_t)row * EQ;
    o[t]       = tobf(d0 * rs * w[t]       + b[t]);
    o[t + 256] = tobf(d1 * rs * w[t + 256] + b[t + 256]);
    o[t + 512] = tobf(d2 * rs * w[t + 512] + b[t + 512]);
}

// ---------------- bf16 MFMA GEMM: C = A(MxK) @ Bt(NxK)^T, 128x128 tile ------
enum { EPI_NONE = 0, EPI_RES = 1, EPI_BIAS_GELU = 2, EPI_BIAS_RES = 3 };

template<int EPI, bool OUTBF16>
__global__ __launch_bounds__(256) void mgemm(
    const void* __restrict__ A, const void* __restrict__ Bt,
    void* __restrict__ Cm, const float* __restrict__ bias,
    const float* __restrict__ res, int M, int N, int K)
{
    __shared__ __align__(16) unsigned short As[128 * 32];
    __shared__ __align__(16) unsigned short Bs[128 * 32];
    const int tid = threadIdx.x;
    const int lane = tid & 63;
    const int w = tid >> 6;
    const int wr = w >> 1, wc = w & 1;
    const int l15 = lane & 15, quad = lane >> 4;
    const int row0 = blockIdx.x * 128, col0 = blockIdx.y * 128;

    f32x4 acc[4][4] = {};

    const char* Ab = (const char*)A;
    const char* Bb = (const char*)Bt;

    for (int k0 = 0; k0 < K; k0 += 32) {
        #pragma unroll
        for (int c = 0; c < 2; ++c) {
            int ch = c * 256 + tid;
            const char* ga = Ab + ((size_t)(row0 + (ch >> 2)) * K + k0) * 2 + (ch & 3) * 16;
            async16(ga, (char*)As + (size_t)(c * 256 + w * 64) * 16);
            const char* gb = Bb + ((size_t)(col0 + (ch >> 2)) * K + k0) * 2 + (ch & 3) * 16;
            async16(gb, (char*)Bs + (size_t)(c * 256 + w * 64) * 16);
        }
        __syncthreads();
        bf16x8 af[4], bfr[4];
        #pragma unroll
        for (int i = 0; i < 4; ++i)
            af[i] = *(const bf16x8*)&As[(wr * 64 + i * 16 + l15) * 32 + quad * 8];
        #pragma unroll
        for (int j = 0; j < 4; ++j)
            bfr[j] = *(const bf16x8*)&Bs[(wc * 64 + j * 16 + l15) * 32 + quad * 8];
        #pragma unroll
        for (int i = 0; i < 4; ++i)
            #pragma unroll
            for (int j = 0; j < 4; ++j)
                acc[i][j] = __builtin_amdgcn_mfma_f32_16x16x32_bf16(af[i], bfr[j], acc[i][j], 0, 0, 0);
        __syncthreads();
    }

    #pragma unroll
    for (int j = 0; j < 4; ++j) {
        int c = col0 + wc * 64 + j * 16 + l15;
        float bv = 0.f;
        if (EPI == EPI_BIAS_GELU || EPI == EPI_BIAS_RES) bv = bias[c];
        #pragma unroll
        for (int i = 0; i < 4; ++i) {
            #pragma unroll
            for (int rg = 0; rg < 4; ++rg) {
                int r = row0 + wr * 64 + i * 16 + quad * 4 + rg;
                if (r < M) {
                    float v = acc[i][j][rg];
                    size_t idx = (size_t)r * N + c;
                    if (EPI == EPI_RES) {
                        v += res[idx];
                    } else if (EPI == EPI_BIAS_GELU) {
                        v += bv;
                        v = 0.5f * v * (1.0f + erff(v * 0.70710678118654752f));
                    } else if (EPI == EPI_BIAS_RES) {
                        v += bv + res[idx];
                    }
                    if (OUTBF16) ((__hip_bfloat16*)Cm)[idx] = tobf(v);
                    else         ((float*)Cm)[idx] = v;
                }
            }
        }
    }
}

// ------------- fused scores+softmax: per (s-tile, bh) block -----------------
// qkv: [MPAD rows][2304] bf16, q at col h*64, k at col 768+h*64
// att out: [bh*197+s][256] bf16, cols t>=197 written as 0
__global__ __launch_bounds__(256) void attn_sm(
    const unsigned short* __restrict__ qkv, unsigned short* __restrict__ att)
{
    const int s0 = blockIdx.x * 64;
    const int bh = blockIdx.y;
    const int b = bh / HQ, h = bh % HQ;
    const int tid = threadIdx.x;
    const int w = tid >> 6;            // col chunk (t-chunk of 64)
    const int lane = tid & 63;
    const int l15 = lane & 15, quad = lane >> 4;
    __shared__ float redm[4][64], reds[4][64];

    const size_t qbase = ((size_t)b * SQ) * QKV3 + h * DHQ;        // q cols
    const size_t kbase = qbase + EQ;                               // k cols

    f32x4 acc[4][4] = {};
    #pragma unroll
    for (int ks = 0; ks < 2; ++ks) {
        bf16x8 af[4], bfr[4];
        #pragma unroll
        for (int i = 0; i < 4; ++i)
            af[i] = *(const bf16x8*)(qkv + qbase + (size_t)(s0 + i * 16 + l15) * QKV3 + ks * 32 + quad * 8);
        #pragma unroll
        for (int j = 0; j < 4; ++j)
            bfr[j] = *(const bf16x8*)(qkv + kbase + (size_t)(w * 64 + j * 16 + l15) * QKV3 + ks * 32 + quad * 8);
        #pragma unroll
        for (int i = 0; i < 4; ++i)
            #pragma unroll
            for (int j = 0; j < 4; ++j)
                acc[i][j] = __builtin_amdgcn_mfma_f32_16x16x32_bf16(af[i], bfr[j], acc[i][j], 0, 0, 0);
    }

    const float scale = 0.07124704998790965f;  // 1/sqrt(197)
    float sc[4][4][4];                         // [i][rg][j]
    #pragma unroll
    for (int i = 0; i < 4; ++i)
        #pragma unroll
        for (int j = 0; j < 4; ++j) {
            bool ok = (w * 64 + j * 16 + l15) < SQ;
            #pragma unroll
            for (int rg = 0; rg < 4; ++rg)
                sc[i][rg][j] = ok ? acc[i][j][rg] * scale : -1e30f;
        }

    // per-row max: lane-local over j, shuffle over the 16 col-lanes, LDS across waves
    #pragma unroll
    for (int i = 0; i < 4; ++i)
        #pragma unroll
        for (int rg = 0; rg < 4; ++rg) {
            float m = fmaxf(fmaxf(sc[i][rg][0], sc[i][rg][1]), fmaxf(sc[i][rg][2], sc[i][rg][3]));
            #pragma unroll
            for (int d = 1; d < 16; d <<= 1) m = fmaxf(m, __shfl_xor(m, d));
            if (l15 == 0) redm[w][i * 16 + quad * 4 + rg] = m;
        }
    __syncthreads();

    float tot[4][4];  // row sums
    #pragma unroll
    for (int i = 0; i < 4; ++i)
        #pragma unroll
        for (int rg = 0; rg < 4; ++rg) {
            int row = i * 16 + quad * 4 + rg;
            float m = fmaxf(fmaxf(redm[0][row], redm[1][row]),
                            fmaxf(redm[2][row], redm[3][row]));
            float s = 0.f;
            #pragma unroll
            for (int j = 0; j < 4; ++j) {
                float e = expf(sc[i][rg][j] - m);
                sc[i][rg][j] = e;
                s += e;
            }
            #pragma unroll
            for (int d = 1; d < 16; d <<= 1) s += __shfl_xor(s, d);
            if (l15 == 0) reds[w][row] = s;
            tot[i][rg] = 0.f;
        }
    __syncthreads();

    #pragma unroll
    for (int i = 0; i < 4; ++i)
        #pragma unroll
        for (int rg = 0; rg < 4; ++rg) {
            int row = i * 16 + quad * 4 + rg;
            tot[i][rg] = reds[0][row] + reds[1][row] + reds[2][row] + reds[3][row];
        }

    #pragma unroll
    for (int i = 0; i < 4; ++i)
        #pragma unroll
        for (int rg = 0; rg < 4; ++rg) {
            int srow = s0 + i * 16 + quad * 4 + rg;
            if (srow < SQ) {
                float inv = 1.0f / tot[i][rg];
                __hip_bfloat16* ap = (__hip_bfloat16*)att +
                    ((size_t)bh * SQ + srow) * TPAD + w * 64 + l15;
                #pragma unroll
                for (int j = 0; j < 4; ++j)
                    ap[j * 16] = tobf(sc[i][rg][j] * inv);
            }
        }
}

// ------------- o = att @ v : per (s-tile, bh) block, V^T staged in LDS ------
__global__ __launch_bounds__(256) void attv_mfma(
    const unsigned short* __restrict__ att, const unsigned short* __restrict__ qkv,
    __hip_bfloat16* __restrict__ o)
{
    __shared__ unsigned short Vs[64][264];   // [d][t], stride 264 breaks conflicts
    const int s0 = blockIdx.x * 64;
    const int bh = blockIdx.y;
    const int b = bh / HQ, h = bh % HQ;
    const int tid = threadIdx.x;
    const int w = tid >> 6, lane = tid & 63;
    const int wr = w >> 1, wc = w & 1;
    const int l15 = lane & 15, quad = lane >> 4;

    // stage V^T: Vs[d][t] = v[(b*197+t)][h*64+d]; v at qkv col 1536+h*64
    const size_t vbase = ((size_t)b * SQ) * QKV3 + 2 * EQ + h * DHQ;
    {
        int t = tid;  // 0..255
        #pragma unroll
        for (int dch = 0; dch < 16; ++dch) {
            ushort4 u = *(const ushort4*)(qkv + vbase + (size_t)t * QKV3 + dch * 4);
            Vs[dch * 4 + 0][t] = u.x;
            Vs[dch * 4 + 1][t] = u.y;
            Vs[dch * 4 + 2][t] = u.z;
            Vs[dch * 4 + 3][t] = u.w;
        }
    }
    __syncthreads();

    const size_t arow = (size_t)bh * SQ + s0;
    f32x4 acc[2][2] = {};
    #pragma unroll
    for (int ks = 0; ks < 8; ++ks) {
        bf16x8 af[2], bfr[2];
        #pragma unroll
        for (int i = 0; i < 2; ++i)
            af[i] = *(const bf16x8*)(att + (arow + wr * 32 + i * 16 + l15) * TPAD + ks * 32 + quad * 8);
        #pragma unroll
        for (int j = 0; j < 2; ++j)
            bfr[j] = *(const bf16x8*)&Vs[wc * 32 + j * 16 + l15][ks * 32 + quad * 8];
        #pragma unroll
        for (int i = 0; i < 2; ++i)
            #pragma unroll
            for (int j = 0; j < 2; ++j)
                acc[i][j] = __builtin_amdgcn_mfma_f32_16x16x32_bf16(af[i], bfr[j], acc[i][j], 0, 0, 0);
    }

    #pragma unroll
    for (int i = 0; i < 2; ++i)
        #pragma unroll
        for (int rg = 0; rg < 4; ++rg) {
            int srow = s0 + wr * 32 + i * 16 + quad * 4 + rg;
            if (srow < SQ) {
                __hip_bfloat16* op = o + ((size_t)b * SQ + srow) * EQ + h * DHQ + wc * 32 + l15;
                #pragma unroll
                for (int j = 0; j < 2; ++j)
                    op[j * 16] = tobf(acc[i][j][rg]);
            }
        }
}

// ---------------- classifier: logits GEMV (parallel) + softmax --------------
__global__ __launch_bounds__(256) void logits_kernel(
    const float* __restrict__ hbuf, const float* __restrict__ Wc,
    const float* __restrict__ bc, float* __restrict__ logits)
{
    __shared__ __align__(16) float hs[768];
    int b = blockIdx.y;
    int c = blockIdx.x * 256 + threadIdx.x;
    const float* hr = hbuf + (size_t)b * SQ * EQ;   // s=0 row
    for (int p = threadIdx.x; p < 192; p += 256)
        *(float4*)&hs[p << 2] = *(const float4*)(hr + (p << 2));
    __syncthreads();
    if (c < CQ) {
        float s = bc[c];
        #pragma unroll 8
        for (int e = 0; e < EQ; ++e)
            s = fmaf(hs[e], Wc[(size_t)e * CQ + c], s);
        logits[(size_t)b * CQ + c] = s;
    }
}

__global__ __launch_bounds__(256) void smax_kernel(
    const float* __restrict__ logits, float* __restrict__ out)
{
    __shared__ float red[256];
    int b = blockIdx.x;
    int t = threadIdx.x;
    const float* lp = logits + (size_t)b * CQ;
    float lg[4];
    #pragma unroll
    for (int j = 0; j < 4; ++j) {
        int c = t + j * 256;
        lg[j] = (c < CQ) ? lp[c] : -1e30f;
    }
    float m = fmaxf(fmaxf(lg[0], lg[1]), fmaxf(lg[2], lg[3]));
    red[t] = m;
    __syncthreads();
    for (int off = 128; off; off >>= 1) {
        if (t < off) red[t] = fmaxf(red[t], red[t + off]);
        __syncthreads();
    }
    m = red[0];
    __syncthreads();
    float ex[4], s = 0.f;
    #pragma unroll
    for (int j = 0; j < 4; ++j) {
        ex[j] = (t + j * 256 < CQ) ? expf(lg[j] - m) : 0.f;
        s += ex[j];
    }
    red[t] = s;
    __syncthreads();
    for (int off = 128; off; off >>= 1) {
        if (t < off) red[t] += red[t + off];
        __syncthreads();
    }
    float inv = 1.0f / red[0];
    #pragma unroll
    for (int j = 0; j < 4; ++j)
        if (t + j * 256 < CQ) out[(size_t)b * CQ + t + j * 256] = ex[j] * inv;
}

extern "C" void kernel_launch(void* const* d_in, const int* in_sizes, int n_in,
                              void* d_out, int out_size, void* d_ws, size_t ws_size,
                              hipStream_t stream)
{
    const float* x     = (const float*)d_in[0];
    const float* Wk    = (const float*)d_in[1];
    const float* Wq    = (const float*)d_in[2];
    const float* Wv    = (const float*)d_in[3];
    const float* Wconv = (const float*)d_in[4];
    const float* ln1w  = (const float*)d_in[5];
    const float* ln1b  = (const float*)d_in[6];
    const float* ln2w  = (const float*)d_in[7];
    const float* ln2b  = (const float*)d_in[8];
    const float* W1    = (const float*)d_in[9];
    const float* b1    = (const float*)d_in[10];
    const float* W2    = (const float*)d_in[11];
    const float* b2    = (const float*)d_in[12];
    const float* Wc    = (const float*)d_in[13];
    const float* bc    = (const float*)d_in[14];
    float* out = (float*)d_out;

    const size_t BSE   = (size_t)BSQ * EQ;
    const size_t ATTR  = (size_t)BQ * HQ * SQ + 64;   // att rows + overflow pad

    float* w = (float*)d_ws;
    float* bh    = w; w += BSE;                       // residual out
    float* res1  = w; w += BSE;                       // post-attn residual
    float* logit = w; w += (size_t)BQ * CQ;           // classifier logits
    __hip_bfloat16* qkvbf = (__hip_bfloat16*)w; w += (size_t)MPAD * QKV3 / 2;
    __hip_bfloat16* actb  = (__hip_bfloat16*)w; w += (size_t)MPAD * EQ / 2;
    __hip_bfloat16* attbf = (__hip_bfloat16*)w; w += ATTR * TPAD / 2;
    __hip_bfloat16* wbuf  = (__hip_bfloat16*)w;
    __hip_bfloat16* ffh   = attbf;                    // MPAD x F overlays attbf

    const size_t WQKV = (size_t)EQ * EQ;
    __hip_bfloat16* WqT = wbuf;                       // phase A: q|k|v stacked (2304 x 768)
    __hip_bfloat16* WkT = wbuf + WQKV;
    __hip_bfloat16* WvT = wbuf + 2 * WQKV;
    __hip_bfloat16* WcvT = wbuf;                      // phase B overlays
    __hip_bfloat16* W1T  = wbuf + WQKV;
    __hip_bfloat16* W2T  = W1T + (size_t)EQ * FQ;

    for (int l = 0; l < LQ; ++l) {
        const float* hin = (l == 0) ? x : bh;
        tconv<<<dim3(12, 1, HQ), 256, 0, stream>>>(Wq + (size_t)l * HQ * EQ * DHQ, WqT, EQ, DHQ, (size_t)EQ * DHQ);
        tconv<<<dim3(12, 1, HQ), 256, 0, stream>>>(Wk + (size_t)l * HQ * EQ * DHQ, WkT, EQ, DHQ, (size_t)EQ * DHQ);
        tconv<<<dim3(12, 1, HQ), 256, 0, stream>>>(Wv + (size_t)l * HQ * EQ * DHQ, WvT, EQ, DHQ, (size_t)EQ * DHQ);

        ln_kernel<<<BSQ, 256, 0, stream>>>(hin, ln1w + l * EQ, ln1b + l * EQ, actb);

        // fused QKV: N = 2304, Bt = [WqT; WkT; WvT]
        mgemm<EPI_NONE, true><<<dim3(50, 18), 256, 0, stream>>>(actb, WqT, qkvbf, nullptr, nullptr, BSQ, QKV3, EQ);

        // phase B weight converts (wbuf free after QKV mgemm, stream-ordered)
        tconv<<<dim3(12, 12, 1), 256, 0, stream>>>(Wconv + (size_t)l * EQ * EQ, WcvT, EQ, EQ, 0);
        tconv<<<dim3(12, 32, 1), 256, 0, stream>>>(W1 + (size_t)l * EQ * FQ, W1T, EQ, FQ, 0);
        tconv<<<dim3(32, 12, 1), 256, 0, stream>>>(W2 + (size_t)l * FQ * EQ, W2T, FQ, EQ, 0);

        attn_sm<<<dim3(4, BQ * HQ), 256, 0, stream>>>((const unsigned short*)qkvbf, (unsigned short*)attbf);
        attv_mfma<<<dim3(4, BQ * HQ), 256, 0, stream>>>((const unsigned short*)attbf, (const unsigned short*)qkvbf, actb);

        mgemm<EPI_RES, false><<<dim3(50, 6), 256, 0, stream>>>(actb, WcvT, res1, nullptr, hin, BSQ, EQ, EQ);

        ln_kernel<<<BSQ, 256, 0, stream>>>(res1, ln2w + l * EQ, ln2b + l * EQ, actb);

        mgemm<EPI_BIAS_GELU, true><<<dim3(50, 16), 256, 0, stream>>>(actb, W1T, ffh, b1 + l * FQ, nullptr, BSQ, FQ, EQ);
        mgemm<EPI_BIAS_RES, false><<<dim3(50, 6), 256, 0, stream>>>(ffh, W2T, bh, b2 + l * EQ, res1, BSQ, EQ, FQ);
    }
    logits_kernel<<<dim3(4, BQ), 256, 0, stream>>>(bh, Wc, bc, logit);
    smax_kernel<<<BQ, 256, 0, stream>>>(logit, out);
}

// Round 4
// 1348.471 us; speedup vs baseline: 3.6127x; 1.1188x over previous
//
#include <hip/hip_runtime.h>
#include <hip/hip_bf16.h>
#include <math.h>

#define BQ 32
#define SQ 197
#define EQ 768
#define HQ 12
#define DHQ 64
#define FQ 2048
#define LQ 4
#define CQ 1000
#define BSQ (BQ*SQ)     // 6304
#define MPAD 6400       // 6304 padded to 128-multiple for MFMA A-tiles
#define QKV3 2304       // fused q|k|v row width
#define TPAD 256        // attention t-dim padded
#define LN_EPS 1e-5f

typedef __bf16 bf16x8 __attribute__((ext_vector_type(8)));
typedef float f32x4 __attribute__((ext_vector_type(4)));

typedef __attribute__((address_space(1))) void gvoid;
typedef __attribute__((address_space(3))) void lvoid;

__device__ __forceinline__ void async16(const void* g, void* l) {
    __builtin_amdgcn_global_load_lds((gvoid*)g, (lvoid*)l, 16, 0, 0);
}

__device__ __forceinline__ __hip_bfloat16 tobf(float f) { return __float2bfloat16(f); }

// ---------------- transpose + fp32->bf16 convert: out[c][r] = in[r][c] ------
__global__ __launch_bounds__(256) void tconv(const float* __restrict__ in,
    __hip_bfloat16* __restrict__ out, int R, int C, size_t slab)
{
    __shared__ float tile[64][65];
    const float* ip = in + (size_t)blockIdx.z * slab;
    __hip_bfloat16* op = out + (size_t)blockIdx.z * slab;
    int r0 = blockIdx.x * 64, c0 = blockIdx.y * 64;
    int t = threadIdx.x;
    int tc = t & 63, tr = t >> 6;
    #pragma unroll
    for (int p = 0; p < 16; ++p) {
        int r = p * 4 + tr;
        tile[r][tc] = ip[(size_t)(r0 + r) * C + c0 + tc];
    }
    __syncthreads();
    #pragma unroll
    for (int p = 0; p < 16; ++p) {
        int c = p * 4 + tr;
        op[(size_t)(c0 + c) * R + r0 + tc] = tobf(tile[tc][c]);
    }
}

// ---------------- LayerNorm: fp32 in -> bf16 out ----------------------------
__global__ __launch_bounds__(256) void ln_kernel(const float* __restrict__ in,
    const float* __restrict__ w, const float* __restrict__ b,
    __hip_bfloat16* __restrict__ out)
{
    int row = blockIdx.x;
    const float* x = in + (size_t)row * EQ;
    int t = threadIdx.x;
    float v0 = x[t];
    float v1 = x[t + 256];
    float v2 = x[t + 512];
    __shared__ float red[256];
    red[t] = v0 + v1 + v2;
    __syncthreads();
    for (int off = 128; off > 0; off >>= 1) {
        if (t < off) red[t] += red[t + off];
        __syncthreads();
    }
    float mu = red[0] * (1.0f / EQ);
    __syncthreads();
    float d0 = v0 - mu, d1 = v1 - mu, d2 = v2 - mu;
    red[t] = d0*d0 + d1*d1 + d2*d2;
    __syncthreads();
    for (int off = 128; off > 0; off >>= 1) {
        if (t < off) red[t] += red[t + off];
        __syncthreads();
    }
    float rs = rsqrtf(red[0] * (1.0f / EQ) + LN_EPS);
    __hip_bfloat16* o = out + (size_t)row * EQ;
    o[t]       = tobf(d0 * rs * w[t]       + b[t]);
    o[t + 256] = tobf(d1 * rs * w[t + 256] + b[t + 256]);
    o[t + 512] = tobf(d2 * rs * w[t + 512] + b[t + 512]);
}

// ---------------- bf16 MFMA GEMM: C = A(MxK) @ Bt(NxK)^T --------------------
// Tile: (IM*32) x 128, 4 waves in 2x2. Double-buffered LDS, swizzled chunks.
// Chunk q (16B) of row r stored at slot (q + (r>>1)) & 3  -> 2-way bank access.
enum { EPI_NONE = 0, EPI_RES = 1, EPI_BIAS_GELU = 2, EPI_BIAS_RES = 3 };

template<int EPI, bool OUTBF16, int IM>
__global__ __launch_bounds__(256) void mgemm(
    const void* __restrict__ A, const void* __restrict__ Bt,
    void* __restrict__ Cm, const float* __restrict__ bias,
    const float* __restrict__ res, int M, int N, int K)
{
    __shared__ __align__(16) unsigned short As[2][IM * 1024];   // IM*32 rows x 32
    __shared__ __align__(16) unsigned short Bs[2][4096];        // 128 rows x 32
    const int tid = threadIdx.x;
    const int lane = tid & 63;
    const int w = tid >> 6;
    const int wr = w >> 1, wc = w & 1;
    const int l15 = lane & 15, quad = lane >> 4;
    const int row0 = blockIdx.x * (IM * 32), col0 = blockIdx.y * 128;

    const char* Ab = (const char*)A;
    const char* Bb = (const char*)Bt;

    auto stage = [&](int buf, int k0) {
        #pragma unroll
        for (int c = 0; c < IM / 2; ++c) {
            int ch = c * 256 + tid;
            int row = ch >> 2, slot = ch & 3;
            int q = (slot - (row >> 1)) & 3;
            const char* ga = Ab + ((size_t)(row0 + row) * K + k0) * 2 + q * 16;
            async16(ga, (char*)&As[buf][0] + (size_t)ch * 16);
        }
        #pragma unroll
        for (int c = 0; c < 2; ++c) {
            int ch = c * 256 + tid;
            int row = ch >> 2, slot = ch & 3;
            int q = (slot - (row >> 1)) & 3;
            const char* gb = Bb + ((size_t)(col0 + row) * K + k0) * 2 + q * 16;
            async16(gb, (char*)&Bs[buf][0] + (size_t)ch * 16);
        }
    };

    f32x4 acc[IM][4] = {};
    const int nk = K >> 5;
    stage(0, 0);
    int cur = 0;
    for (int k = 0; k < nk; ++k) {
        __syncthreads();                       // drains prev prefetch (vmcnt0)
        if (k + 1 < nk) stage(cur ^ 1, (k + 1) << 5);
        bf16x8 af[IM], bfr[4];
        #pragma unroll
        for (int i = 0; i < IM; ++i) {
            int r = wr * (IM * 16) + i * 16 + l15;
            int slot = (quad + (r >> 1)) & 3;
            af[i] = *(const bf16x8*)&As[cur][r * 32 + slot * 8];
        }
        #pragma unroll
        for (int j = 0; j < 4; ++j) {
            int r = wc * 64 + j * 16 + l15;
            int slot = (quad + (r >> 1)) & 3;
            bfr[j] = *(const bf16x8*)&Bs[cur][r * 32 + slot * 8];
        }
        #pragma unroll
        for (int i = 0; i < IM; ++i)
            #pragma unroll
            for (int j = 0; j < 4; ++j)
                acc[i][j] = __builtin_amdgcn_mfma_f32_16x16x32_bf16(af[i], bfr[j], acc[i][j], 0, 0, 0);
        cur ^= 1;
    }

    #pragma unroll
    for (int j = 0; j < 4; ++j) {
        int c = col0 + wc * 64 + j * 16 + l15;
        float bv = 0.f;
        if (EPI == EPI_BIAS_GELU || EPI == EPI_BIAS_RES) bv = bias[c];
        #pragma unroll
        for (int i = 0; i < IM; ++i) {
            #pragma unroll
            for (int rg = 0; rg < 4; ++rg) {
                int r = row0 + wr * (IM * 16) + i * 16 + quad * 4 + rg;
                if (r < M) {
                    float v = acc[i][j][rg];
                    size_t idx = (size_t)r * N + c;
                    if (EPI == EPI_RES) {
                        v += res[idx];
                    } else if (EPI == EPI_BIAS_GELU) {
                        v += bv;
                        v = 0.5f * v * (1.0f + erff(v * 0.70710678118654752f));
                    } else if (EPI == EPI_BIAS_RES) {
                        v += bv + res[idx];
                    }
                    if (OUTBF16) ((__hip_bfloat16*)Cm)[idx] = tobf(v);
                    else         ((float*)Cm)[idx] = v;
                }
            }
        }
    }
}

// ------------- fused scores+softmax: per (s-tile, bh) block -----------------
__global__ __launch_bounds__(256) void attn_sm(
    const unsigned short* __restrict__ qkv, unsigned short* __restrict__ att)
{
    const int s0 = blockIdx.x * 64;
    const int bh = blockIdx.y;
    const int b = bh / HQ, h = bh % HQ;
    const int tid = threadIdx.x;
    const int w = tid >> 6;
    const int lane = tid & 63;
    const int l15 = lane & 15, quad = lane >> 4;
    __shared__ float redm[4][64], reds[4][64];

    const size_t qbase = ((size_t)b * SQ) * QKV3 + h * DHQ;
    const size_t kbase = qbase + EQ;

    f32x4 acc[4][4] = {};
    #pragma unroll
    for (int ks = 0; ks < 2; ++ks) {
        bf16x8 af[4], bfr[4];
        #pragma unroll
        for (int i = 0; i < 4; ++i)
            af[i] = *(const bf16x8*)(qkv + qbase + (size_t)(s0 + i * 16 + l15) * QKV3 + ks * 32 + quad * 8);
        #pragma unroll
        for (int j = 0; j < 4; ++j)
            bfr[j] = *(const bf16x8*)(qkv + kbase + (size_t)(w * 64 + j * 16 + l15) * QKV3 + ks * 32 + quad * 8);
        #pragma unroll
        for (int i = 0; i < 4; ++i)
            #pragma unroll
            for (int j = 0; j < 4; ++j)
                acc[i][j] = __builtin_amdgcn_mfma_f32_16x16x32_bf16(af[i], bfr[j], acc[i][j], 0, 0, 0);
    }

    const float scale = 0.07124704998790965f;  // 1/sqrt(197)
    float sc[4][4][4];
    #pragma unroll
    for (int i = 0; i < 4; ++i)
        #pragma unroll
        for (int j = 0; j < 4; ++j) {
            bool ok = (w * 64 + j * 16 + l15) < SQ;
            #pragma unroll
            for (int rg = 0; rg < 4; ++rg)
                sc[i][rg][j] = ok ? acc[i][j][rg] * scale : -1e30f;
        }

    #pragma unroll
    for (int i = 0; i < 4; ++i)
        #pragma unroll
        for (int rg = 0; rg < 4; ++rg) {
            float m = fmaxf(fmaxf(sc[i][rg][0], sc[i][rg][1]), fmaxf(sc[i][rg][2], sc[i][rg][3]));
            #pragma unroll
            for (int d = 1; d < 16; d <<= 1) m = fmaxf(m, __shfl_xor(m, d));
            if (l15 == 0) redm[w][i * 16 + quad * 4 + rg] = m;
        }
    __syncthreads();

    float tot[4][4];
    #pragma unroll
    for (int i = 0; i < 4; ++i)
        #pragma unroll
        for (int rg = 0; rg < 4; ++rg) {
            int row = i * 16 + quad * 4 + rg;
            float m = fmaxf(fmaxf(redm[0][row], redm[1][row]),
                            fmaxf(redm[2][row], redm[3][row]));
            float s = 0.f;
            #pragma unroll
            for (int j = 0; j < 4; ++j) {
                float e = expf(sc[i][rg][j] - m);
                sc[i][rg][j] = e;
                s += e;
            }
            #pragma unroll
            for (int d = 1; d < 16; d <<= 1) s += __shfl_xor(s, d);
            if (l15 == 0) reds[w][row] = s;
            tot[i][rg] = 0.f;
        }
    __syncthreads();

    #pragma unroll
    for (int i = 0; i < 4; ++i)
        #pragma unroll
        for (int rg = 0; rg < 4; ++rg) {
            int row = i * 16 + quad * 4 + rg;
            tot[i][rg] = reds[0][row] + reds[1][row] + reds[2][row] + reds[3][row];
        }

    #pragma unroll
    for (int i = 0; i < 4; ++i)
        #pragma unroll
        for (int rg = 0; rg < 4; ++rg) {
            int srow = s0 + i * 16 + quad * 4 + rg;
            if (srow < SQ) {
                float inv = 1.0f / tot[i][rg];
                __hip_bfloat16* ap = (__hip_bfloat16*)att +
                    ((size_t)bh * SQ + srow) * TPAD + w * 64 + l15;
                #pragma unroll
                for (int j = 0; j < 4; ++j)
                    ap[j * 16] = tobf(sc[i][rg][j] * inv);
            }
        }
}

// ------------- o = att @ v : per (s-tile, bh) block, V^T staged in LDS ------
__global__ __launch_bounds__(256) void attv_mfma(
    const unsigned short* __restrict__ att, const unsigned short* __restrict__ qkv,
    __hip_bfloat16* __restrict__ o)
{
    __shared__ unsigned short Vs[64][264];
    const int s0 = blockIdx.x * 64;
    const int bh = blockIdx.y;
    const int b = bh / HQ, h = bh % HQ;
    const int tid = threadIdx.x;
    const int w = tid >> 6, lane = tid & 63;
    const int wr = w >> 1, wc = w & 1;
    const int l15 = lane & 15, quad = lane >> 4;

    const size_t vbase = ((size_t)b * SQ) * QKV3 + 2 * EQ + h * DHQ;
    {
        int t = tid;
        #pragma unroll
        for (int dch = 0; dch < 16; ++dch) {
            ushort4 u = *(const ushort4*)(qkv + vbase + (size_t)t * QKV3 + dch * 4);
            Vs[dch * 4 + 0][t] = u.x;
            Vs[dch * 4 + 1][t] = u.y;
            Vs[dch * 4 + 2][t] = u.z;
            Vs[dch * 4 + 3][t] = u.w;
        }
    }
    __syncthreads();

    const size_t arow = (size_t)bh * SQ + s0;
    f32x4 acc[2][2] = {};
    #pragma unroll
    for (int ks = 0; ks < 8; ++ks) {
        bf16x8 af[2], bfr[2];
        #pragma unroll
        for (int i = 0; i < 2; ++i)
            af[i] = *(const bf16x8*)(att + (arow + wr * 32 + i * 16 + l15) * TPAD + ks * 32 + quad * 8);
        #pragma unroll
        for (int j = 0; j < 2; ++j)
            bfr[j] = *(const bf16x8*)&Vs[wc * 32 + j * 16 + l15][ks * 32 + quad * 8];
        #pragma unroll
        for (int i = 0; i < 2; ++i)
            #pragma unroll
            for (int j = 0; j < 2; ++j)
                acc[i][j] = __builtin_amdgcn_mfma_f32_16x16x32_bf16(af[i], bfr[j], acc[i][j], 0, 0, 0);
    }

    #pragma unroll
    for (int i = 0; i < 2; ++i)
        #pragma unroll
        for (int rg = 0; rg < 4; ++rg) {
            int srow = s0 + wr * 32 + i * 16 + quad * 4 + rg;
            if (srow < SQ) {
                __hip_bfloat16* op = o + ((size_t)b * SQ + srow) * EQ + h * DHQ + wc * 32 + l15;
                #pragma unroll
                for (int j = 0; j < 2; ++j)
                    op[j * 16] = tobf(acc[i][j][rg]);
            }
        }
}

// ---------------- classifier: logits GEMV (parallel) + softmax --------------
__global__ __launch_bounds__(256) void logits_kernel(
    const float* __restrict__ hbuf, const float* __restrict__ Wc,
    const float* __restrict__ bc, float* __restrict__ logits)
{
    __shared__ __align__(16) float hs[768];
    int b = blockIdx.y;
    int c = blockIdx.x * 256 + threadIdx.x;
    const float* hr = hbuf + (size_t)b * SQ * EQ;
    for (int p = threadIdx.x; p < 192; p += 256)
        *(float4*)&hs[p << 2] = *(const float4*)(hr + (p << 2));
    __syncthreads();
    if (c < CQ) {
        float s = bc[c];
        #pragma unroll 8
        for (int e = 0; e < EQ; ++e)
            s = fmaf(hs[e], Wc[(size_t)e * CQ + c], s);
        logits[(size_t)b * CQ + c] = s;
    }
}

__global__ __launch_bounds__(256) void smax_kernel(
    const float* __restrict__ logits, float* __restrict__ out)
{
    __shared__ float red[256];
    int b = blockIdx.x;
    int t = threadIdx.x;
    const float* lp = logits + (size_t)b * CQ;
    float lg[4];
    #pragma unroll
    for (int j = 0; j < 4; ++j) {
        int c = t + j * 256;
        lg[j] = (c < CQ) ? lp[c] : -1e30f;
    }
    float m = fmaxf(fmaxf(lg[0], lg[1]), fmaxf(lg[2], lg[3]));
    red[t] = m;
    __syncthreads();
    for (int off = 128; off; off >>= 1) {
        if (t < off) red[t] = fmaxf(red[t], red[t + off]);
        __syncthreads();
    }
    m = red[0];
    __syncthreads();
    float ex[4], s = 0.f;
    #pragma unroll
    for (int j = 0; j < 4; ++j) {
        ex[j] = (t + j * 256 < CQ) ? expf(lg[j] - m) : 0.f;
        s += ex[j];
    }
    red[t] = s;
    __syncthreads();
    for (int off = 128; off; off >>= 1) {
        if (t < off) red[t] += red[t + off];
        __syncthreads();
    }
    float inv = 1.0f / red[0];
    #pragma unroll
    for (int j = 0; j < 4; ++j)
        if (t + j * 256 < CQ) out[(size_t)b * CQ + t + j * 256] = ex[j] * inv;
}

extern "C" void kernel_launch(void* const* d_in, const int* in_sizes, int n_in,
                              void* d_out, int out_size, void* d_ws, size_t ws_size,
                              hipStream_t stream)
{
    const float* x     = (const float*)d_in[0];
    const float* Wk    = (const float*)d_in[1];
    const float* Wq    = (const float*)d_in[2];
    const float* Wv    = (const float*)d_in[3];
    const float* Wconv = (const float*)d_in[4];
    const float* ln1w  = (const float*)d_in[5];
    const float* ln1b  = (const float*)d_in[6];
    const float* ln2w  = (const float*)d_in[7];
    const float* ln2b  = (const float*)d_in[8];
    const float* W1    = (const float*)d_in[9];
    const float* b1    = (const float*)d_in[10];
    const float* W2    = (const float*)d_in[11];
    const float* b2    = (const float*)d_in[12];
    const float* Wc    = (const float*)d_in[13];
    const float* bc    = (const float*)d_in[14];
    float* out = (float*)d_out;

    const size_t BSE   = (size_t)BSQ * EQ;
    const size_t ATTR  = (size_t)BQ * HQ * SQ + 64;

    float* w = (float*)d_ws;
    float* bh    = w; w += BSE;
    float* res1  = w; w += BSE;
    float* logit = w; w += (size_t)BQ * CQ;
    __hip_bfloat16* qkvbf = (__hip_bfloat16*)w; w += (size_t)MPAD * QKV3 / 2;
    __hip_bfloat16* actb  = (__hip_bfloat16*)w; w += (size_t)MPAD * EQ / 2;
    __hip_bfloat16* attbf = (__hip_bfloat16*)w; w += ATTR * TPAD / 2;
    __hip_bfloat16* wbuf  = (__hip_bfloat16*)w;
    __hip_bfloat16* ffh   = attbf;

    const size_t WQKV = (size_t)EQ * EQ;
    __hip_bfloat16* WqT = wbuf;
    __hip_bfloat16* WkT = wbuf + WQKV;
    __hip_bfloat16* WvT = wbuf + 2 * WQKV;
    __hip_bfloat16* WcvT = wbuf;
    __hip_bfloat16* W1T  = wbuf + WQKV;
    __hip_bfloat16* W2T  = W1T + (size_t)EQ * FQ;

    for (int l = 0; l < LQ; ++l) {
        const float* hin = (l == 0) ? x : bh;
        tconv<<<dim3(12, 1, HQ), 256, 0, stream>>>(Wq + (size_t)l * HQ * EQ * DHQ, WqT, EQ, DHQ, (size_t)EQ * DHQ);
        tconv<<<dim3(12, 1, HQ), 256, 0, stream>>>(Wk + (size_t)l * HQ * EQ * DHQ, WkT, EQ, DHQ, (size_t)EQ * DHQ);
        tconv<<<dim3(12, 1, HQ), 256, 0, stream>>>(Wv + (size_t)l * HQ * EQ * DHQ, WvT, EQ, DHQ, (size_t)EQ * DHQ);

        ln_kernel<<<BSQ, 256, 0, stream>>>(hin, ln1w + l * EQ, ln1b + l * EQ, actb);

        mgemm<EPI_NONE, true, 4><<<dim3(50, 18), 256, 0, stream>>>(actb, WqT, qkvbf, nullptr, nullptr, BSQ, QKV3, EQ);

        tconv<<<dim3(12, 12, 1), 256, 0, stream>>>(Wconv + (size_t)l * EQ * EQ, WcvT, EQ, EQ, 0);
        tconv<<<dim3(12, 32, 1), 256, 0, stream>>>(W1 + (size_t)l * EQ * FQ, W1T, EQ, FQ, 0);
        tconv<<<dim3(32, 12, 1), 256, 0, stream>>>(W2 + (size_t)l * FQ * EQ, W2T, FQ, EQ, 0);

        attn_sm<<<dim3(4, BQ * HQ), 256, 0, stream>>>((const unsigned short*)qkvbf, (unsigned short*)attbf);
        attv_mfma<<<dim3(4, BQ * HQ), 256, 0, stream>>>((const unsigned short*)attbf, (const unsigned short*)qkvbf, actb);

        mgemm<EPI_RES, false, 2><<<dim3(100, 6), 256, 0, stream>>>(actb, WcvT, res1, nullptr, hin, BSQ, EQ, EQ);

        ln_kernel<<<BSQ, 256, 0, stream>>>(res1, ln2w + l * EQ, ln2b + l * EQ, actb);

        mgemm<EPI_BIAS_GELU, true, 4><<<dim3(50, 16), 256, 0, stream>>>(actb, W1T, ffh, b1 + l * FQ, nullptr, BSQ, FQ, EQ);
        mgemm<EPI_BIAS_RES, false, 2><<<dim3(100, 6), 256, 0, stream>>>(ffh, W2T, bh, b2 + l * EQ, res1, BSQ, EQ, FQ);
    }
    logits_kernel<<<dim3(4, BQ), 256, 0, stream>>>(bh, Wc, bc, logit);
    smax_kernel<<<BQ, 256, 0, stream>>>(logit, out);
}